// Round 1
// baseline (926.911 us; speedup 1.0000x reference)
//
#include <hip/hip_runtime.h>

#define N_NODES 10000
#define E_EDGES 320000
#define ND 256
#define ED 128

// ---- workspace layout (float indices); total ~33.9 MB ----
#define WS_AM   0
#define WS_BM   2560000
#define WS_AE   5120000
#define WS_BE   6400000
#define WS_P1   7680000
#define WS_P2   7690240
#define WS_ATT  7700480
#define WS_EX   8020480
#define WS_DEN  8340480
#define WS_SMX  8350720
#define WS_WT   8360960

// weight table byte offsets within wtb; layout [Ncols][K] bf16 (K-contiguous)
#define M0T 0
#define M1T 65536
#define M2T 196608
#define E0T 327680
#define E1T 360448
#define E2T 393216

// ---- LDS byte offsets for k_main ----
#define EA_S   0
#define H0E_S  32768
#define H1E_S  65536
#define H0M_S  32768
#define H1M_LO 0
#define H1M_HI 98304
#define AL_S   131072
#define SRC_S  131584
#define DST_S  132096
#define LDS_TOT 132608

#define BM 128

typedef float  float4v __attribute__((ext_vector_type(4)));
typedef short  short8  __attribute__((ext_vector_type(8)));

__device__ __forceinline__ unsigned short f2bf(float f) {
    unsigned int b = __float_as_uint(f);
    return (unsigned short)((b + 0x7FFFu + ((b >> 16) & 1u)) >> 16);
}
#define PK2(a,b) ((unsigned int)(a) | ((unsigned int)(b) << 16))

// ---------------- zero init ----------------
__global__ void k_zero(float* xout, float* den, unsigned int* smx) {
    int i = blockIdx.x * blockDim.x + threadIdx.x;
    int st = gridDim.x * blockDim.x;
    for (int j = i; j < N_NODES * ND; j += st) xout[j] = 0.f;
    for (int j = i; j < N_NODES; j += st) { den[j] = 0.f; smx[j] = 0u; }
}

// ---------------- weight transpose/convert to bf16 [N][K] ----------------
__global__ void k_wconv(const float* mw0, const float* mw1, const float* mw2,
                        const float* ew0, const float* ew1, const float* ew2, char* wtb) {
    const int tot = 212992;
    for (int idx = blockIdx.x * blockDim.x + threadIdx.x; idx < tot;
         idx += gridDim.x * blockDim.x) {
        int local, K, N, base; const float* src;
        if (idx < 32768)       { local = idx;          K = 128; N = 256; src = mw0 + 512*256; base = M0T; }
        else if (idx < 98304)  { local = idx - 32768;  K = 256; N = 256; src = mw1;           base = M1T; }
        else if (idx < 163840) { local = idx - 98304;  K = 256; N = 256; src = mw2;           base = M2T; }
        else if (idx < 180224) { local = idx - 163840; K = 128; N = 128; src = ew0 + 512*128; base = E0T; }
        else if (idx < 196608) { local = idx - 180224; K = 128; N = 128; src = ew1;           base = E1T; }
        else                   { local = idx - 196608; K = 128; N = 128; src = ew2;           base = E2T; }
        int c = local / K, k = local % K;
        ((unsigned short*)(wtb + base))[local] = f2bf(src[k * N + c]);
    }
}

// ---------------- node precompute: [10000,256] @ [256,770] fp32 ----------------
__global__ __launch_bounds__(256) void k_nodepre(
    const float* na, const float* mw0, const float* ew0, const float* aw,
    const float* mb0, const float* eb0, const float* ab, float* ws) {
    __shared__ float at[256 * 32];
    int tid = threadIdx.x;
    int r0 = blockIdx.x * 32;
    int nr = N_NODES - r0; if (nr > 32) nr = 32;
    {
        int r = tid & 31, kq = tid >> 5;
        if (r < nr) {
            const float* src = na + (size_t)(r0 + r) * ND + kq * 32;
            for (int i = 0; i < 32; i += 4) {
                float4 v = *(const float4*)(src + i);
                at[(kq*32 + i + 0)*32 + r] = v.x;
                at[(kq*32 + i + 1)*32 + r] = v.y;
                at[(kq*32 + i + 2)*32 + r] = v.z;
                at[(kq*32 + i + 3)*32 + r] = v.w;
            }
        } else {
            for (int i = 0; i < 32; i++) at[(kq*32 + i)*32 + r] = 0.f;
        }
    }
    __syncthreads();
    int c = blockIdx.y * 256 + tid;
    if (c >= 770) return;
    const float* wp; int wstep; float bias; float* op; int ostride;
    float* Am = ws + WS_AM; float* Bm = ws + WS_BM;
    float* Ae = ws + WS_AE; float* Be = ws + WS_BE;
    float* p1 = ws + WS_P1; float* p2 = ws + WS_P2;
    if (c < 256)      { wp = mw0 + c;                 wstep = 256; bias = mb0[c];     op = Am + c;       ostride = 256; }
    else if (c < 512) { wp = mw0 + 65536 + (c - 256); wstep = 256; bias = 0.f;        op = Bm + (c-256); ostride = 256; }
    else if (c < 640) { wp = ew0 + (c - 512);         wstep = 128; bias = eb0[c-512]; op = Ae + (c-512); ostride = 128; }
    else if (c < 768) { wp = ew0 + 32768 + (c - 640); wstep = 128; bias = 0.f;        op = Be + (c-640); ostride = 128; }
    else if (c == 768){ wp = aw;                      wstep = 1;   bias = ab[0];      op = p1;           ostride = 1; }
    else              { wp = aw + 256;                wstep = 1;   bias = 0.f;        op = p2;           ostride = 1; }
    float acc[32];
    #pragma unroll
    for (int r = 0; r < 32; r++) acc[r] = 0.f;
    for (int k = 0; k < 256; k++) {
        float w = wp[k * wstep];
        const float* a = &at[k * 32];
        #pragma unroll
        for (int r4 = 0; r4 < 8; r4++) {
            float4 a4 = *(const float4*)(a + r4 * 4);
            acc[r4*4+0] += a4.x * w; acc[r4*4+1] += a4.y * w;
            acc[r4*4+2] += a4.z * w; acc[r4*4+3] += a4.w * w;
        }
    }
    for (int r = 0; r < nr; r++) op[(size_t)(r0 + r) * ostride] = acc[r] + bias;
}

// ---------------- att + segment max (monotone-uint atomicMax) ----------------
__global__ __launch_bounds__(256) void k_att(
    const float* ea, const int* ei, const float* aw,
    const float* p1, const float* p2, float* att, unsigned int* smx) {
    __shared__ float awe[128];
    int tid = threadIdx.x;
    if (tid < 128) awe[tid] = aw[512 + tid];
    __syncthreads();
    int e = blockIdx.x * 16 + (tid >> 4);
    int j = tid & 15;
    if (e >= E_EDGES) return;
    const float* row = ea + (size_t)e * ED + j * 8;
    float s = 0.f;
    #pragma unroll
    for (int i = 0; i < 8; i += 4) {
        float4 v = *(const float4*)(row + i);
        float4 w = *(const float4*)(&awe[j * 8 + i]);
        s += v.x*w.x + v.y*w.y + v.z*w.z + v.w*w.w;
    }
    s += __shfl_xor(s, 1); s += __shfl_xor(s, 2);
    s += __shfl_xor(s, 4); s += __shfl_xor(s, 8);
    if (j == 0) {
        int sn = ei[e];
        int dn = ei[E_EDGES + e];
        float a = s + p1[sn] + p2[dn];
        att[e] = a;
        unsigned int b = __float_as_uint(a);
        unsigned int m = (b >> 31) ? ~b : (b | 0x80000000u);
        atomicMax(&smx[sn], m);
    }
}

// ---------------- exp + segment sum ----------------
__global__ void k_exp(const float* att, const int* ei, const unsigned int* smx,
                      float* ex, float* den) {
    int e = blockIdx.x * 256 + threadIdx.x;
    if (e >= E_EDGES) return;
    int sn = ei[e];
    unsigned int u = smx[sn];
    unsigned int b = (u & 0x80000000u) ? (u ^ 0x80000000u) : ~u;
    float m = __uint_as_float(b);
    float v = __expf(att[e] - m);
    ex[e] = v;
    unsafeAtomicAdd(&den[sn], v);
}

// ---------------- fused per-edge MLP main kernel ----------------
struct DP {
    const float* ea; const int* ei;
    const float* Am; const float* Bm; const float* Ae; const float* Be;
    const float* ex; const float* den;
    const float* mb1; const float* mb2; const float* eb1; const float* eb2;
    const char* wtb;
    float* xout; float* eout;
};

template<bool SPLIT>
__device__ __forceinline__ int a_addr(int base, int stride, int row, int ke) {
    if constexpr (!SPLIT) return base + row * stride + ((ke * 2) ^ ((row & 7) << 4));
    else {
        int half = ke >> 7; int k = ke & 127;
        return (half ? H1M_HI : H1M_LO) + row * 256 + ((k * 2) ^ ((row & 7) << 4));
    }
}
template<bool SPLIT>
__device__ __forceinline__ int h_addr(int base, int stride, int row, int col) {
    if constexpr (!SPLIT) return base + row * stride + ((col * 2) ^ ((row & 7) << 4));
    else {
        int half = col >> 7; int c = col & 127;
        return (half ? H1M_HI : H1M_LO) + row * 256 + ((c * 2) ^ ((row & 7) << 4));
    }
}

// EPI: 0=m0(Am/Bm gather+relu->h) 1=bias+relu->h 2=m2(mb2,*alpha,atomic x_out)
//      3=e0(Ae/Be gather+relu->h) 4=e2(eb2->e_out)
template<int KTOT, int NOUT, int EPI, bool ASPLIT, bool HSPLIT>
__device__ __forceinline__ void do_gemm(char* sm, const DP& p, int e0,
                                        int a_base, int a_stride, int wt_byte,
                                        int h_base, int h_stride, const float* bias,
                                        int wv, int lane) {
    constexpr int CF   = (NOUT == 256) ? 4 : 2;
    constexpr int WCOL = (NOUT == 256) ? 64 : 32;
    constexpr int NK  = KTOT / 32;
    constexpr int KH  = (NK > 4) ? 2 : 1;
    constexpr int NKH = NK / KH;
    const int wr = wv >> 2, wc = wv & 3;
    const int l15 = lane & 15, lg = lane >> 4;
    const float4v vz = {0.f, 0.f, 0.f, 0.f};
    float4v acc[4][CF];
    #pragma unroll
    for (int i = 0; i < 4; i++)
        #pragma unroll
        for (int j = 0; j < CF; j++) acc[i][j] = vz;
    const char* wt = p.wtb + wt_byte;
    __syncthreads();
    #pragma unroll
    for (int kh = 0; kh < KH; kh++) {
        short8 b[NKH][CF];   // weights live in registers, streamed from L2 once
        #pragma unroll
        for (int ks = 0; ks < NKH; ks++)
            #pragma unroll
            for (int cf = 0; cf < CF; cf++) {
                int col = wc * WCOL + cf * 16 + l15;
                int ke  = kh * 128 + ks * 32 + lg * 8;
                b[ks][cf] = *(const short8*)(wt + ((size_t)col * KTOT + ke) * 2);
            }
        #pragma unroll
        for (int ks = 0; ks < NKH; ks++) {
            short8 a[4];
            int ke = kh * 128 + ks * 32 + lg * 8;
            #pragma unroll
            for (int rf = 0; rf < 4; rf++) {
                int row = wr * 64 + rf * 16 + l15;
                a[rf] = *(const short8*)(sm + a_addr<ASPLIT>(a_base, a_stride, row, ke));
            }
            #pragma unroll
            for (int rf = 0; rf < 4; rf++)
                #pragma unroll
                for (int cf = 0; cf < CF; cf++)
                    acc[rf][cf] = __builtin_amdgcn_mfma_f32_16x16x32_bf16(a[rf], b[ks][cf], acc[rf][cf], 0, 0, 0);
        }
    }
    // epilogue (C layout: col = lane&15, row = (lane>>4)*4 + reg  [m89-verified])
    const int*   srcid = (const int*)(sm + SRC_S);
    const int*   dstid = (const int*)(sm + DST_S);
    const float* alph  = (const float*)(sm + AL_S);
    #pragma unroll
    for (int rf = 0; rf < 4; rf++)
        #pragma unroll
        for (int cf = 0; cf < CF; cf++)
            #pragma unroll
            for (int j = 0; j < 4; j++) {
                int row = wr * 64 + rf * 16 + lg * 4 + j;
                int col = wc * WCOL + cf * 16 + l15;
                float v = acc[rf][cf][j];
                if constexpr (EPI == 0) {
                    v += p.Am[(size_t)srcid[row] * ND + col] + p.Bm[(size_t)dstid[row] * ND + col];
                    v = fmaxf(v, 0.f);
                    *(unsigned short*)(sm + h_addr<HSPLIT>(h_base, h_stride, row, col)) = f2bf(v);
                } else if constexpr (EPI == 1) {
                    v += bias[col]; v = fmaxf(v, 0.f);
                    *(unsigned short*)(sm + h_addr<HSPLIT>(h_base, h_stride, row, col)) = f2bf(v);
                } else if constexpr (EPI == 2) {
                    v += p.mb2[col]; v *= alph[row];
                    unsafeAtomicAdd(&p.xout[(size_t)srcid[row] * ND + col], v);
                } else if constexpr (EPI == 3) {
                    v += p.Ae[(size_t)srcid[row] * ED + col] + p.Be[(size_t)dstid[row] * ED + col];
                    v = fmaxf(v, 0.f);
                    *(unsigned short*)(sm + h_addr<HSPLIT>(h_base, h_stride, row, col)) = f2bf(v);
                } else {
                    v += p.eb2[col];
                    p.eout[(size_t)(e0 + row) * ED + col] = v;
                }
            }
}

__global__ __launch_bounds__(512, 2) void k_main(DP p) {
    extern __shared__ char sm[];
    const int tid = threadIdx.x;
    const int lane = tid & 63, wv = tid >> 6;
    const int e0 = blockIdx.x * BM;

    if (tid < BM) {
        int sn = p.ei[e0 + tid];
        int dn = p.ei[E_EDGES + e0 + tid];
        ((int*)(sm + SRC_S))[tid] = sn;
        ((int*)(sm + DST_S))[tid] = dn;
        ((float*)(sm + AL_S))[tid] = p.ex[e0 + tid] / p.den[sn];
    }
    // stage edge_attr [128][128] f32 -> bf16, XOR-swizzled, row stride 256B
    {
        int r = tid >> 2, cq = tid & 3;
        const float4* src = (const float4*)(p.ea + (size_t)(e0 + r) * ED + cq * 32);
        int s = (r & 7) << 4;
        #pragma unroll
        for (int h = 0; h < 2; h++) {
            float4 v0 = src[h*4+0], v1 = src[h*4+1], v2 = src[h*4+2], v3 = src[h*4+3];
            unsigned short u[16] = {f2bf(v0.x),f2bf(v0.y),f2bf(v0.z),f2bf(v0.w),
                                    f2bf(v1.x),f2bf(v1.y),f2bf(v1.z),f2bf(v1.w),
                                    f2bf(v2.x),f2bf(v2.y),f2bf(v2.z),f2bf(v2.w),
                                    f2bf(v3.x),f2bf(v3.y),f2bf(v3.z),f2bf(v3.w)};
            int cb = cq * 64 + h * 32;
            *(uint4*)(sm + EA_S + r*256 + ((cb)      ^ s)) =
                make_uint4(PK2(u[0],u[1]), PK2(u[2],u[3]), PK2(u[4],u[5]), PK2(u[6],u[7]));
            *(uint4*)(sm + EA_S + r*256 + ((cb + 16) ^ s)) =
                make_uint4(PK2(u[8],u[9]), PK2(u[10],u[11]), PK2(u[12],u[13]), PK2(u[14],u[15]));
        }
    }
    // e-chain first (ea stays live until m0; h-regions free)
    do_gemm<128,128,3,false,false>(sm, p, e0, EA_S, 256, E0T, H0E_S, 256, nullptr, wv, lane);
    do_gemm<128,128,1,false,false>(sm, p, e0, H0E_S,256, E1T, H1E_S, 256, p.eb1,  wv, lane);
    do_gemm<128,128,4,false,false>(sm, p, e0, H1E_S,256, E2T, 0, 0,      nullptr, wv, lane);
    // m-chain
    do_gemm<128,256,0,false,false>(sm, p, e0, EA_S, 256, M0T, H0M_S, 512, nullptr, wv, lane);
    do_gemm<256,256,1,false,true >(sm, p, e0, H0M_S,512, M1T, 0, 0,      p.mb1,  wv, lane);
    do_gemm<256,256,2,true ,false>(sm, p, e0, 0, 0,      M2T, 0, 0,      nullptr, wv, lane);
}

extern "C" void kernel_launch(void* const* d_in, const int* in_sizes, int n_in,
                              void* d_out, int out_size, void* d_ws, size_t ws_size,
                              hipStream_t stream) {
    const float* na  = (const float*)d_in[0];
    const float* ea  = (const float*)d_in[1];
    const int*   ei  = (const int*)d_in[2];
    const float* mw0 = (const float*)d_in[3];
    const float* mb0 = (const float*)d_in[4];
    const float* mw1 = (const float*)d_in[5];
    const float* mb1 = (const float*)d_in[6];
    const float* mw2 = (const float*)d_in[7];
    const float* mb2 = (const float*)d_in[8];
    const float* ew0 = (const float*)d_in[9];
    const float* eb0 = (const float*)d_in[10];
    const float* ew1 = (const float*)d_in[11];
    const float* eb1 = (const float*)d_in[12];
    const float* ew2 = (const float*)d_in[13];
    const float* eb2 = (const float*)d_in[14];
    const float* aw  = (const float*)d_in[15];
    const float* ab  = (const float*)d_in[16];
    float* out = (float*)d_out;
    float* wsf = (float*)d_ws;

    float* xout = out;
    float* eout = out + (size_t)N_NODES * ND;

    k_zero<<<512, 256, 0, stream>>>(xout, wsf + WS_DEN, (unsigned int*)(wsf + WS_SMX));
    k_wconv<<<256, 256, 0, stream>>>(mw0, mw1, mw2, ew0, ew1, ew2, (char*)(wsf + WS_WT));
    k_nodepre<<<dim3(313, 4), 256, 0, stream>>>(na, mw0, ew0, aw, mb0, eb0, ab, wsf);
    k_att<<<20000, 256, 0, stream>>>(ea, ei, aw, wsf + WS_P1, wsf + WS_P2,
                                     wsf + WS_ATT, (unsigned int*)(wsf + WS_SMX));
    k_exp<<<1250, 256, 0, stream>>>(wsf + WS_ATT, ei, (const unsigned int*)(wsf + WS_SMX),
                                    wsf + WS_EX, wsf + WS_DEN);

    DP p{ea, ei, wsf + WS_AM, wsf + WS_BM, wsf + WS_AE, wsf + WS_BE,
         wsf + WS_EX, wsf + WS_DEN, mb1, mb2, eb1, eb2,
         (const char*)(wsf + WS_WT), xout, eout};
    hipFuncSetAttribute((const void*)k_main, hipFuncAttributeMaxDynamicSharedMemorySize, LDS_TOT);
    k_main<<<E_EDGES / BM, 512, LDS_TOT, stream>>>(p);
}

// Round 2
// 882.097 us; speedup vs baseline: 1.0508x; 1.0508x over previous
//
#include <hip/hip_runtime.h>

#define N_NODES 10000
#define E_EDGES 320000
#define ND 256
#define ED 128

// ---- workspace layout (float indices); total ~33.9 MB ----
#define WS_AM   0
#define WS_BM   2560000
#define WS_AE   5120000
#define WS_BE   6400000
#define WS_P1   7680000
#define WS_P2   7690240
#define WS_ATT  7700480
#define WS_EX   8020480
#define WS_DEN  8340480
#define WS_SMX  8350720
#define WS_WT   8360960

// weight table byte offsets within wtb; layout [Ncols][K] bf16 (K-contiguous)
#define M0T 0
#define M1T 65536
#define M2T 196608
#define E0T 327680
#define E1T 360448
#define E2T 393216

// ---- LDS layout for k_main: four 16KB panels [64 rows][256B], swizzled ----
#define R0 0
#define R1 16384
#define R2 32768
#define R3 49152
#define AL_S  65536
#define SRC_S 65792
#define DST_S 66048
#define LDS_TOT 66304

#define BM 64   // edges per block

typedef float  float4v __attribute__((ext_vector_type(4)));
typedef short  short8  __attribute__((ext_vector_type(8)));

__device__ __forceinline__ unsigned short f2bf(float f) {
    unsigned int b = __float_as_uint(f);
    return (unsigned short)((b + 0x7FFFu + ((b >> 16) & 1u)) >> 16);
}
#define PK2(a,b) ((unsigned int)(a) | ((unsigned int)(b) << 16))

// ---------------- zero init ----------------
__global__ void k_zero(float* xout, float* den, unsigned int* smx) {
    int i = blockIdx.x * blockDim.x + threadIdx.x;
    int st = gridDim.x * blockDim.x;
    for (int j = i; j < N_NODES * ND; j += st) xout[j] = 0.f;
    for (int j = i; j < N_NODES; j += st) { den[j] = 0.f; smx[j] = 0u; }
}

// ---------------- weight transpose/convert to bf16 [N][K] ----------------
__global__ void k_wconv(const float* mw0, const float* mw1, const float* mw2,
                        const float* ew0, const float* ew1, const float* ew2, char* wtb) {
    const int tot = 212992;
    for (int idx = blockIdx.x * blockDim.x + threadIdx.x; idx < tot;
         idx += gridDim.x * blockDim.x) {
        int local, K, N, base; const float* src;
        if (idx < 32768)       { local = idx;          K = 128; N = 256; src = mw0 + 512*256; base = M0T; }
        else if (idx < 98304)  { local = idx - 32768;  K = 256; N = 256; src = mw1;           base = M1T; }
        else if (idx < 163840) { local = idx - 98304;  K = 256; N = 256; src = mw2;           base = M2T; }
        else if (idx < 180224) { local = idx - 163840; K = 128; N = 128; src = ew0 + 512*128; base = E0T; }
        else if (idx < 196608) { local = idx - 180224; K = 128; N = 128; src = ew1;           base = E1T; }
        else                   { local = idx - 196608; K = 128; N = 128; src = ew2;           base = E2T; }
        int c = local / K, k = local % K;
        ((unsigned short*)(wtb + base))[local] = f2bf(src[k * N + c]);
    }
}

// ---------------- node precompute: [10000,256] @ [256,770] fp32 ----------------
__global__ __launch_bounds__(256) void k_nodepre(
    const float* na, const float* mw0, const float* ew0, const float* aw,
    const float* mb0, const float* eb0, const float* ab, float* ws) {
    __shared__ float at[256 * 32];
    int tid = threadIdx.x;
    int r0 = blockIdx.x * 32;
    int nr = N_NODES - r0; if (nr > 32) nr = 32;
    {
        int r = tid & 31, kq = tid >> 5;
        if (r < nr) {
            const float* src = na + (size_t)(r0 + r) * ND + kq * 32;
            for (int i = 0; i < 32; i += 4) {
                float4 v = *(const float4*)(src + i);
                at[(kq*32 + i + 0)*32 + r] = v.x;
                at[(kq*32 + i + 1)*32 + r] = v.y;
                at[(kq*32 + i + 2)*32 + r] = v.z;
                at[(kq*32 + i + 3)*32 + r] = v.w;
            }
        } else {
            for (int i = 0; i < 32; i++) at[(kq*32 + i)*32 + r] = 0.f;
        }
    }
    __syncthreads();
    int c = blockIdx.y * 256 + tid;
    if (c >= 770) return;
    const float* wp; int wstep; float bias; float* op; int ostride;
    float* Am = ws + WS_AM; float* Bm = ws + WS_BM;
    float* Ae = ws + WS_AE; float* Be = ws + WS_BE;
    float* p1 = ws + WS_P1; float* p2 = ws + WS_P2;
    if (c < 256)      { wp = mw0 + c;                 wstep = 256; bias = mb0[c];     op = Am + c;       ostride = 256; }
    else if (c < 512) { wp = mw0 + 65536 + (c - 256); wstep = 256; bias = 0.f;        op = Bm + (c-256); ostride = 256; }
    else if (c < 640) { wp = ew0 + (c - 512);         wstep = 128; bias = eb0[c-512]; op = Ae + (c-512); ostride = 128; }
    else if (c < 768) { wp = ew0 + 32768 + (c - 640); wstep = 128; bias = 0.f;        op = Be + (c-640); ostride = 128; }
    else if (c == 768){ wp = aw;                      wstep = 1;   bias = ab[0];      op = p1;           ostride = 1; }
    else              { wp = aw + 256;                wstep = 1;   bias = 0.f;        op = p2;           ostride = 1; }
    float acc[32];
    #pragma unroll
    for (int r = 0; r < 32; r++) acc[r] = 0.f;
    for (int k = 0; k < 256; k++) {
        float w = wp[k * wstep];
        const float* a = &at[k * 32];
        #pragma unroll
        for (int r4 = 0; r4 < 8; r4++) {
            float4 a4 = *(const float4*)(a + r4 * 4);
            acc[r4*4+0] += a4.x * w; acc[r4*4+1] += a4.y * w;
            acc[r4*4+2] += a4.z * w; acc[r4*4+3] += a4.w * w;
        }
    }
    for (int r = 0; r < nr; r++) op[(size_t)(r0 + r) * ostride] = acc[r] + bias;
}

// ---------------- att + segment max (monotone-uint atomicMax) ----------------
__global__ __launch_bounds__(256) void k_att(
    const float* ea, const int* ei, const float* aw,
    const float* p1, const float* p2, float* att, unsigned int* smx) {
    __shared__ float awe[128];
    int tid = threadIdx.x;
    if (tid < 128) awe[tid] = aw[512 + tid];
    __syncthreads();
    int e = blockIdx.x * 16 + (tid >> 4);
    int j = tid & 15;
    if (e >= E_EDGES) return;
    const float* row = ea + (size_t)e * ED + j * 8;
    float s = 0.f;
    #pragma unroll
    for (int i = 0; i < 8; i += 4) {
        float4 v = *(const float4*)(row + i);
        float4 w = *(const float4*)(&awe[j * 8 + i]);
        s += v.x*w.x + v.y*w.y + v.z*w.z + v.w*w.w;
    }
    s += __shfl_xor(s, 1); s += __shfl_xor(s, 2);
    s += __shfl_xor(s, 4); s += __shfl_xor(s, 8);
    if (j == 0) {
        int sn = ei[e];
        int dn = ei[E_EDGES + e];
        float a = s + p1[sn] + p2[dn];
        att[e] = a;
        unsigned int b = __float_as_uint(a);
        unsigned int m = (b >> 31) ? ~b : (b | 0x80000000u);
        atomicMax(&smx[sn], m);
    }
}

// ---------------- exp + segment sum ----------------
__global__ void k_exp(const float* att, const int* ei, const unsigned int* smx,
                      float* ex, float* den) {
    int e = blockIdx.x * 256 + threadIdx.x;
    if (e >= E_EDGES) return;
    int sn = ei[e];
    unsigned int u = smx[sn];
    unsigned int b = (u & 0x80000000u) ? (u ^ 0x80000000u) : ~u;
    float m = __uint_as_float(b);
    float v = __expf(att[e] - m);
    ex[e] = v;
    unsafeAtomicAdd(&den[sn], v);
}

// ---------------- fused per-edge MLP main kernel ----------------
struct DP {
    const float* ea; const int* ei;
    const float* Am; const float* Bm; const float* Ae; const float* Be;
    const float* ex; const float* den;
    const float* mb1; const float* mb2; const float* eb1; const float* eb2;
    const char* wtb;
    float* xout; float* eout;
};

// panel pair addressing: 256-col buffers live in (lo,hi) 16KB panels,
// 128-col buffers in lo only. byte = base + row*256 + ((col&127)*2 ^ ((row&7)<<4))
__device__ __forceinline__ int pan_addr(int blo, int bhi, int row, int col) {
    int base = (col & 128) ? bhi : blo;
    return base + row * 256 + ((((col & 127)) * 2) ^ ((row & 7) << 4));
}

// EPI: 0=m0(Am/Bm gather+relu->h) 1=bias+relu->h 2=m2(mb2,*alpha,atomic x_out)
//      3=e0(Ae/Be gather+relu->h) 4=e2(eb2->e_out)
template<int KTOT, int NOUT, int EPI>
__device__ __forceinline__ void do_gemm(char* sm, const DP& p, int e0,
                                        int a_lo, int a_hi, int wt_byte,
                                        int h_lo, int h_hi, const float* bias,
                                        int wv, int lane) {
    constexpr int CF   = (NOUT == 256) ? 4 : 2;
    constexpr int WCOL = (NOUT == 256) ? 64 : 32;
    constexpr int NK   = KTOT / 32;
    constexpr int KH   = (NK * CF > 8) ? (NK * CF / 8) : 1;   // keep b[] <= 8 short8
    constexpr int NKH  = NK / KH;
    const int wr = wv >> 2, wc = wv & 3;
    const int l15 = lane & 15, lg = lane >> 4;
    const float4v vz = {0.f, 0.f, 0.f, 0.f};
    float4v acc[2][CF];
    #pragma unroll
    for (int i = 0; i < 2; i++)
        #pragma unroll
        for (int j = 0; j < CF; j++) acc[i][j] = vz;
    const char* wt = p.wtb + wt_byte;
    __syncthreads();
    #pragma unroll
    for (int kh = 0; kh < KH; kh++) {
        short8 b[NKH][CF];   // weights live in registers, streamed from L2
        #pragma unroll
        for (int ks = 0; ks < NKH; ks++)
            #pragma unroll
            for (int cf = 0; cf < CF; cf++) {
                int col = wc * WCOL + cf * 16 + l15;
                int ke  = (kh * NKH + ks) * 32 + lg * 8;
                b[ks][cf] = *(const short8*)(wt + ((size_t)col * KTOT + ke) * 2);
            }
        #pragma unroll
        for (int ks = 0; ks < NKH; ks++) {
            short8 a[2];
            int ke = (kh * NKH + ks) * 32 + lg * 8;
            #pragma unroll
            for (int rf = 0; rf < 2; rf++) {
                int row = wr * 32 + rf * 16 + l15;
                a[rf] = *(const short8*)(sm + pan_addr(a_lo, a_hi, row, ke));
            }
            #pragma unroll
            for (int rf = 0; rf < 2; rf++)
                #pragma unroll
                for (int cf = 0; cf < CF; cf++)
                    acc[rf][cf] = __builtin_amdgcn_mfma_f32_16x16x32_bf16(a[rf], b[ks][cf], acc[rf][cf], 0, 0, 0);
        }
    }
    // epilogue (C layout: col = lane&15, row = (lane>>4)*4 + reg  [m89-verified])
    const int*   srcid = (const int*)(sm + SRC_S);
    const int*   dstid = (const int*)(sm + DST_S);
    const float* alph  = (const float*)(sm + AL_S);
    #pragma unroll
    for (int rf = 0; rf < 2; rf++)
        #pragma unroll
        for (int cf = 0; cf < CF; cf++)
            #pragma unroll
            for (int j = 0; j < 4; j++) {
                int row = wr * 32 + rf * 16 + lg * 4 + j;
                int col = wc * WCOL + cf * 16 + l15;
                float v = acc[rf][cf][j];
                if constexpr (EPI == 0) {
                    v += p.Am[(size_t)srcid[row] * ND + col] + p.Bm[(size_t)dstid[row] * ND + col];
                    v = fmaxf(v, 0.f);
                    *(unsigned short*)(sm + pan_addr(h_lo, h_hi, row, col)) = f2bf(v);
                } else if constexpr (EPI == 1) {
                    v += bias[col]; v = fmaxf(v, 0.f);
                    *(unsigned short*)(sm + pan_addr(h_lo, h_hi, row, col)) = f2bf(v);
                } else if constexpr (EPI == 2) {
                    v += p.mb2[col]; v *= alph[row];
                    unsafeAtomicAdd(&p.xout[(size_t)srcid[row] * ND + col], v);
                } else if constexpr (EPI == 3) {
                    v += p.Ae[(size_t)srcid[row] * ED + col] + p.Be[(size_t)dstid[row] * ED + col];
                    v = fmaxf(v, 0.f);
                    *(unsigned short*)(sm + pan_addr(h_lo, h_hi, row, col)) = f2bf(v);
                } else {
                    v += p.eb2[col];
                    p.eout[(size_t)(e0 + row) * ED + col] = v;
                }
            }
}

__global__ __launch_bounds__(512, 4) void k_main(DP p) {
    extern __shared__ char sm[];
    const int tid = threadIdx.x;
    const int lane = tid & 63, wv = tid >> 6;
    const int e0 = blockIdx.x * BM;

    if (tid < BM) {
        int sn = p.ei[e0 + tid];
        int dn = p.ei[E_EDGES + e0 + tid];
        ((int*)(sm + SRC_S))[tid] = sn;
        ((int*)(sm + DST_S))[tid] = dn;
        ((float*)(sm + AL_S))[tid] = p.ex[e0 + tid] / p.den[sn];
    }
    // stage edge_attr [64][128] f32 -> bf16 into R0, XOR-swizzled, row stride 256B
    {
        int r = tid >> 3, cq = tid & 7;                 // 16 floats per thread
        const float4* src = (const float4*)(p.ea + (size_t)(e0 + r) * ED + cq * 16);
        int s = (r & 7) << 4;
        float4 v0 = src[0], v1 = src[1], v2 = src[2], v3 = src[3];
        unsigned short u[16] = {f2bf(v0.x),f2bf(v0.y),f2bf(v0.z),f2bf(v0.w),
                                f2bf(v1.x),f2bf(v1.y),f2bf(v1.z),f2bf(v1.w),
                                f2bf(v2.x),f2bf(v2.y),f2bf(v2.z),f2bf(v2.w),
                                f2bf(v3.x),f2bf(v3.y),f2bf(v3.z),f2bf(v3.w)};
        int cb = cq * 32;
        *(uint4*)(sm + R0 + r*256 + (cb ^ s)) =
            make_uint4(PK2(u[0],u[1]), PK2(u[2],u[3]), PK2(u[4],u[5]), PK2(u[6],u[7]));
        *(uint4*)(sm + R0 + r*256 + ((cb + 16) ^ s)) =
            make_uint4(PK2(u[8],u[9]), PK2(u[10],u[11]), PK2(u[12],u[13]), PK2(u[14],u[15]));
    }
    // e-chain (ea in R0 stays live through m0)
    do_gemm<128,128,3>(sm, p, e0, R0, 0,  E0T, R1, 0,  nullptr, wv, lane);
    do_gemm<128,128,1>(sm, p, e0, R1, 0,  E1T, R2, 0,  p.eb1,   wv, lane);
    do_gemm<128,128,4>(sm, p, e0, R2, 0,  E2T, 0,  0,  nullptr, wv, lane);
    // m-chain: h0m -> (R1,R2), h1m -> (R0,R3)
    do_gemm<128,256,0>(sm, p, e0, R0, 0,  M0T, R1, R2, nullptr, wv, lane);
    do_gemm<256,256,1>(sm, p, e0, R1, R2, M1T, R0, R3, p.mb1,   wv, lane);
    do_gemm<256,256,2>(sm, p, e0, R0, R3, M2T, 0,  0,  nullptr, wv, lane);
}

extern "C" void kernel_launch(void* const* d_in, const int* in_sizes, int n_in,
                              void* d_out, int out_size, void* d_ws, size_t ws_size,
                              hipStream_t stream) {
    const float* na  = (const float*)d_in[0];
    const float* ea  = (const float*)d_in[1];
    const int*   ei  = (const int*)d_in[2];
    const float* mw0 = (const float*)d_in[3];
    const float* mb0 = (const float*)d_in[4];
    const float* mw1 = (const float*)d_in[5];
    const float* mb1 = (const float*)d_in[6];
    const float* mw2 = (const float*)d_in[7];
    const float* mb2 = (const float*)d_in[8];
    const float* ew0 = (const float*)d_in[9];
    const float* eb0 = (const float*)d_in[10];
    const float* ew1 = (const float*)d_in[11];
    const float* eb1 = (const float*)d_in[12];
    const float* ew2 = (const float*)d_in[13];
    const float* eb2 = (const float*)d_in[14];
    const float* aw  = (const float*)d_in[15];
    const float* ab  = (const float*)d_in[16];
    float* out = (float*)d_out;
    float* wsf = (float*)d_ws;

    float* xout = out;
    float* eout = out + (size_t)N_NODES * ND;

    k_zero<<<512, 256, 0, stream>>>(xout, wsf + WS_DEN, (unsigned int*)(wsf + WS_SMX));
    k_wconv<<<256, 256, 0, stream>>>(mw0, mw1, mw2, ew0, ew1, ew2, (char*)(wsf + WS_WT));
    k_nodepre<<<dim3(313, 4), 256, 0, stream>>>(na, mw0, ew0, aw, mb0, eb0, ab, wsf);
    k_att<<<20000, 256, 0, stream>>>(ea, ei, aw, wsf + WS_P1, wsf + WS_P2,
                                     wsf + WS_ATT, (unsigned int*)(wsf + WS_SMX));
    k_exp<<<1250, 256, 0, stream>>>(wsf + WS_ATT, ei, (const unsigned int*)(wsf + WS_SMX),
                                    wsf + WS_EX, wsf + WS_DEN);

    DP p{ea, ei, wsf + WS_AM, wsf + WS_BM, wsf + WS_AE, wsf + WS_BE,
         wsf + WS_EX, wsf + WS_DEN, mb1, mb2, eb1, eb2,
         (const char*)(wsf + WS_WT), xout, eout};
    hipFuncSetAttribute((const void*)k_main, hipFuncAttributeMaxDynamicSharedMemorySize, LDS_TOT);
    k_main<<<E_EDGES / BM, 512, LDS_TOT, stream>>>(p);
}